// Round 3
// baseline (375.509 us; speedup 1.0000x reference)
//
#include <hip/hip_runtime.h>
#include <hip/hip_bf16.h>

#define H  4096
#define V  4
#define OUT_N 4
#define MS 104
#define MD 3

// GRU GEMV geometry: one wave per w_hh row; 2 hidden indices per block
// (3 gates x 2 k = 6 waves = 384 threads). 2048 blocks -> ~30 waves/CU.
#define KPB 2
#define TPB (KPB * 3 * 64)
#define NBLK (H / KPB)

__device__ __forceinline__ float b2f(unsigned short u) {
    return __uint_as_float(((unsigned int)u) << 16);
}
__device__ __forceinline__ float ldf(const void* p, size_t i, bool is_f32) {
    return is_f32 ? ((const float*)p)[i] : b2f(((const unsigned short*)p)[i]);
}
__device__ __forceinline__ void stf(void* p, size_t i, bool is_f32, float v) {
    if (is_f32) ((float*)p)[i] = v;
    else        ((__hip_bfloat16*)p)[i] = __float2bfloat16(v);
}

// Wave-uniform dtype detection: decode first 1024 ushorts of w_hh as bf16.
// Real bf16 weights are all |x| <~ 0.2; f32 storage yields random-exponent
// halves (42%/elem chance of |x|>1e6). 2 KB, L1/L2-hot after first wave.
__device__ __forceinline__ bool detect_f32(const void* w_hh) {
    const unsigned short* w = (const unsigned short*)w_hh;
    const int lane = threadIdx.x & 63;
    int bad = 0;
    #pragma unroll
    for (int i = 0; i < 16; ++i) {
        const float v = b2f(w[lane + (i << 6)]);
        if (!(fabsf(v) < 1.0e6f)) bad = 1;
    }
    return __ballot(bad) != 0ull;
}

// 8 bf16 (as uint4) dotted against 8 f32 (two float4).
__device__ __forceinline__ float dot8(uint4 a, float4 h0, float4 h1) {
    return __uint_as_float(a.x << 16)          * h0.x
         + __uint_as_float(a.x & 0xffff0000u)  * h0.y
         + __uint_as_float(a.y << 16)          * h0.z
         + __uint_as_float(a.y & 0xffff0000u)  * h0.w
         + __uint_as_float(a.z << 16)          * h1.x
         + __uint_as_float(a.z & 0xffff0000u)  * h1.y
         + __uint_as_float(a.w << 16)          * h1.z
         + __uint_as_float(a.w & 0xffff0000u)  * h1.w;
}

// ---------------------------------------------------------------------------
// h_bar[j] = w_sh[j,:] . stack[0,:] + b_sh[j] + hidden0[j]  (fp32 into ws).
// Computed ONCE (80 KB reads). Also resets the last-block counter.
// ---------------------------------------------------------------------------
__global__ __launch_bounds__(256) void hbar_kernel(
    const void* __restrict__ w_sh, const void* __restrict__ b_sh,
    const void* __restrict__ hidden0, const void* __restrict__ stack,
    const void* __restrict__ w_hh, float* __restrict__ h_bar,
    int* __restrict__ counter) {
    const bool f32 = detect_f32(w_hh);
    if (blockIdx.x == 0 && threadIdx.x == 0) *counter = 0;
    const float s0 = ldf(stack, 0, f32);
    const float s1 = ldf(stack, 1, f32);
    const float s2 = ldf(stack, 2, f32);
    const int j = blockIdx.x * 256 + threadIdx.x;   // grid is exactly H/256
    h_bar[j] = ldf(w_sh, (size_t)j * 3 + 0, f32) * s0
             + ldf(w_sh, (size_t)j * 3 + 1, f32) * s1
             + ldf(w_sh, (size_t)j * 3 + 2, f32) * s2
             + ldf(b_sh, j, f32) + ldf(hidden0, j, f32);
}

// ---------------------------------------------------------------------------
// GRU GEMV + gates; LAST finishing block also runs the heads (threadfence +
// device-scope atomic counter -- no dispatch-order assumption).
// Stage A: copy precomputed h_bar (16 KB) L2 -> LDS.
// Stage B: one wave per w_hh row, contiguous 16 KB (f32) / 8 KB (bf16)
//          stream, 16 B/lane loads, unroll 8 (8 KB in flight per wave).
// Stage C: t==0 finishes both k's gates (single-writer for the fence).
// Stage D: last block loads h into LDS and computes the 9 head row-dots,
//          softmax/sigmoid, and the differentiable stack blend.
// ---------------------------------------------------------------------------
__global__ __launch_bounds__(TPB) void gru_kernel(
    const int*  __restrict__ inp,  const void* __restrict__ emb,
    const void* __restrict__ w_ih, const void* __restrict__ w_hh,
    const void* __restrict__ b_ih, const void* __restrict__ b_hh,
    const float* __restrict__ h_bar,
    const void* __restrict__ w_y, const void* __restrict__ b_y,
    const void* __restrict__ w_a, const void* __restrict__ b_a,
    const void* __restrict__ w_n, const void* __restrict__ b_n,
    const void* __restrict__ stack,
    float* __restrict__ h_f32, int* __restrict__ counter,
    void* __restrict__ out) {
    const bool f32 = detect_f32(w_hh);
    const int t = threadIdx.x, wave = t >> 6, lane = t & 63;
    const int k0 = blockIdx.x * KPB;

    __shared__ float hb[H];            // h_bar, later reused for h
    __shared__ float red[KPB][3];
    __shared__ int   isLast;

    // ---- Stage A ----------------------------------------------------------
    {
        const float4* src = (const float4*)h_bar;
        float4* dst = (float4*)hb;
        for (int i = t; i < H / 4; i += TPB) dst[i] = src[i];
    }
    __syncthreads();

    // ---- Stage B ----------------------------------------------------------
    const int g  = wave % 3;           // 0=r, 1=z, 2=n (PyTorch gate order)
    const int kk = wave / 3;
    const int row = g * H + k0 + kk;

    float acc = 0.f;
    if (f32) {
        const float4* W  = (const float4*)w_hh + (size_t)row * (H / 4);
        const float4* HB = (const float4*)hb;
        #pragma unroll 8
        for (int it = 0; it < H / 256; ++it) {        // 16 iters
            const int i = (it << 6) + lane;
            const float4 a = W[i], b = HB[i];
            acc += a.x * b.x + a.y * b.y + a.z * b.z + a.w * b.w;
        }
    } else {
        const uint4*  W  = (const uint4*)w_hh + (size_t)row * (H / 8);
        const float4* HB = (const float4*)hb;
        #pragma unroll 8
        for (int it = 0; it < H / 512; ++it) {        // 8 iters
            const int i = (it << 6) + lane;
            acc += dot8(W[i], HB[2 * i], HB[2 * i + 1]);
        }
    }
    #pragma unroll
    for (int off = 32; off > 0; off >>= 1) acc += __shfl_down(acc, off);
    if (lane == 0) red[kk][g] = acc;
    __syncthreads();

    // ---- Stage C: single-writer gate finish + publish ---------------------
    if (t == 0) {
        const int idx = inp[0];
        float x[V];
        #pragma unroll
        for (int c = 0; c < V; ++c) x[c] = ldf(emb, (size_t)idx * V + c, f32);

        #pragma unroll
        for (int kk2 = 0; kk2 < KPB; ++kk2) {
            const int k = k0 + kk2;
            float gi[3];
            #pragma unroll
            for (int gg = 0; gg < 3; ++gg) {
                float a = ldf(b_ih, (size_t)(k + gg * H), f32);
                #pragma unroll
                for (int c = 0; c < V; ++c)
                    a += ldf(w_ih, (size_t)(k + gg * H) * V + c, f32) * x[c];
                gi[gg] = a;
            }
            const float ghr = red[kk2][0] + ldf(b_hh, (size_t)k,           f32);
            const float ghz = red[kk2][1] + ldf(b_hh, (size_t)(k + H),     f32);
            const float ghn = red[kk2][2] + ldf(b_hh, (size_t)(k + 2 * H), f32);

            const float r = 1.f / (1.f + expf(-(gi[0] + ghr)));
            const float z = 1.f / (1.f + expf(-(gi[1] + ghz)));
            const float n = tanhf(gi[2] + r * ghn);
            const float hk = (1.f - z) * n + z * hb[k];

            h_f32[k] = hk;
            stf(out, (size_t)(OUT_N + k), f32, hk);   // hidden output
        }
        __threadfence();                               // release h writes
        isLast = (atomicAdd(counter, 1) == NBLK - 1) ? 1 : 0;
    }
    __syncthreads();
    if (!isLast) return;

    // ---- Stage D: heads, run by the last finishing block ------------------
    __threadfence();                                   // acquire: invalidate L1
    {
        const float4* src = (const float4*)h_f32;
        float4* dst = (float4*)hb;
        for (int i = t; i < H / 4; i += TPB) dst[i] = src[i];
    }
    __syncthreads();

    __shared__ float scal[9];
    for (int r = wave; r < 9; r += TPB / 64) {
        const void* base; size_t ro;
        if (r < 4)      { base = w_y; ro = (size_t)r * H; }
        else if (r < 6) { base = w_a; ro = (size_t)(r - 4) * H; }
        else            { base = w_n; ro = (size_t)(r - 6) * H; }

        float a2 = 0.f;
        if (f32) {
            const float4* W  = (const float4*)((const float*)base + ro);
            const float4* Hv = (const float4*)hb;
            #pragma unroll 8
            for (int it = 0; it < H / 256; ++it) {
                const int i = (it << 6) + lane;
                const float4 w4 = W[i], hv = Hv[i];
                a2 += w4.x * hv.x + w4.y * hv.y + w4.z * hv.z + w4.w * hv.w;
            }
        } else {
            const uint4*  W  = (const uint4*)((const unsigned short*)base + ro);
            const float4* Hv = (const float4*)hb;
            #pragma unroll 8
            for (int it = 0; it < H / 512; ++it) {
                const int i = (it << 6) + lane;
                a2 += dot8(W[i], Hv[2 * i], Hv[2 * i + 1]);
            }
        }
        #pragma unroll
        for (int off = 32; off > 0; off >>= 1) a2 += __shfl_down(a2, off);
        if (lane == 0) scal[r] = a2;
    }
    __syncthreads();

    __shared__ float act0, act1, ne[MD];
    if (t == 0) {
        const float a0 = scal[4] + ldf(b_a, 0, f32);
        const float a1 = scal[5] + ldf(b_a, 1, f32);
        const float m  = fmaxf(a0, a1);
        const float e0 = expf(a0 - m), e1 = expf(a1 - m);
        const float inv = 1.f / (e0 + e1);
        act0 = e0 * inv; act1 = e1 * inv;
    }
    if (t < OUT_N)
        stf(out, (size_t)t, f32,
            1.f / (1.f + expf(-(scal[t] + ldf(b_y, t, f32)))));
    if (t < MD)
        ne[t] = 1.f / (1.f + expf(-(scal[6 + t] + ldf(b_n, t, f32))));
    __syncthreads();

    const float a0 = act0, a1 = act1;
    for (int idx = t; idx < MS * MD; idx += TPB) {
        const int i = idx / MD;
        const int d = idx - i * MD;
        const float push = (i == 0)      ? ne[d] : ldf(stack, (size_t)(idx - MD), f32);
        const float pop  = (i == MS - 1) ? 0.f   : ldf(stack, (size_t)(idx + MD), f32);
        stf(out, (size_t)(OUT_N + H + idx), f32, a0 * push + a1 * pop);
    }
}

extern "C" void kernel_launch(void* const* d_in, const int* in_sizes, int n_in,
                              void* d_out, int out_size, void* d_ws, size_t ws_size,
                              hipStream_t stream) {
    const int* inp      = (const int*)d_in[0];
    const void* hidden0 = d_in[1];
    const void* stack   = d_in[2];
    const void* emb     = d_in[3];
    const void* w_ih    = d_in[4];
    const void* w_hh    = d_in[5];
    const void* b_ih    = d_in[6];
    const void* b_hh    = d_in[7];
    const void* w_y     = d_in[8];
    const void* b_y     = d_in[9];
    const void* w_n     = d_in[10];
    const void* b_n     = d_in[11];
    const void* w_a     = d_in[12];
    const void* b_a     = d_in[13];
    const void* w_sh    = d_in[14];
    const void* b_sh    = d_in[15];

    float* h_bar   = (float*)d_ws;        // H fp32
    float* h       = h_bar + H;           // H fp32
    int*   counter = (int*)(h + H);       // last-block counter (reset by hbar)

    hbar_kernel<<<H / 256, 256, 0, stream>>>(w_sh, b_sh, hidden0, stack,
                                             w_hh, h_bar, counter);
    gru_kernel<<<NBLK, TPB, 0, stream>>>(
        inp, emb, w_ih, w_hh, b_ih, b_hh, h_bar,
        w_y, b_y, w_a, b_a, w_n, b_n, stack, h, counter, d_out);
}

// Round 5
// 331.170 us; speedup vs baseline: 1.1339x; 1.1339x over previous
//
#include <hip/hip_runtime.h>
#include <hip/hip_bf16.h>

#define H  4096
#define V  4
#define OUT_N 4
#define MS 104
#define MD 3

#define R3H (3 * H)            // 12288 rows of w_hh
#define PW  512                // panel width (split-K chunk of H)
#define P   (H / PW)           // 8 panels
#define BPP 256                // blocks per panel
#define RPW (R3H / (BPP * 4))  // rows per wave = 12

__device__ __forceinline__ float b2f(unsigned short u) {
    return __uint_as_float(((unsigned int)u) << 16);
}
__device__ __forceinline__ float ldf(const void* p, size_t i, bool is_f32) {
    return is_f32 ? ((const float*)p)[i] : b2f(((const unsigned short*)p)[i]);
}
__device__ __forceinline__ void stf(void* p, size_t i, bool is_f32, float v) {
    if (is_f32) ((float*)p)[i] = v;
    else        ((__hip_bfloat16*)p)[i] = __float2bfloat16(v);
}

// Wave-uniform dtype detection: decode first 1024 ushorts of w_hh as bf16.
// Real bf16 weights are all |x| <~ 0.2; f32 storage yields random-exponent
// halves (42%/elem chance of |x|>1e6). 2 KB, L1/L2-hot after first wave.
__device__ __forceinline__ bool detect_f32(const void* w_hh) {
    const unsigned short* w = (const unsigned short*)w_hh;
    const int lane = threadIdx.x & 63;
    int bad = 0;
    #pragma unroll
    for (int i = 0; i < 16; ++i) {
        const float v = b2f(w[lane + (i << 6)]);
        if (!(fabsf(v) < 1.0e6f)) bad = 1;
    }
    return __ballot(bad) != 0ull;
}

// 8 bf16 (as uint4) dotted against 8 f32 (two float4).
__device__ __forceinline__ float dot8(uint4 a, float4 h0, float4 h1) {
    return __uint_as_float(a.x << 16)          * h0.x
         + __uint_as_float(a.x & 0xffff0000u)  * h0.y
         + __uint_as_float(a.y << 16)          * h0.z
         + __uint_as_float(a.y & 0xffff0000u)  * h0.w
         + __uint_as_float(a.z << 16)          * h1.x
         + __uint_as_float(a.z & 0xffff0000u)  * h1.y
         + __uint_as_float(a.w << 16)          * h1.z
         + __uint_as_float(a.w & 0xffff0000u)  * h1.w;
}

__device__ __forceinline__ float wave_reduce(float a) {
    #pragma unroll
    for (int off = 32; off > 0; off >>= 1) a += __shfl_down(a, off);
    return a;
}

// Zero the 3H fp32 accumulator (48 KB). 48 blocks x 256.
__global__ __launch_bounds__(256) void zero_kernel(float* __restrict__ acc) {
    acc[blockIdx.x * 256 + threadIdx.x] = 0.f;
}

// ---------------------------------------------------------------------------
// Split-K GEMV partials. Panel p owns h_bar[p*PW, (p+1)*PW). Each lane holds
// its 8-element h_bar slice IN REGISTERS (fuses the hbar kernel; w_sh slice
// reads are L2-hot). Main loop: per row, one uint4 (bf16) / two float4 (f32)
// per lane = fully coalesced 1-2 KB wave segment; 12 independent rows per
// wave in chunks of 4 -> 4+ loads in flight, nothing else on the vmcnt queue.
// Panel partial is atomicAdd'ed into acc[r] (device scope; 8 adds/address).
// 2048 blocks x 256 thr = 8192 waves = 32 waves/CU, zero LDS, ~45 VGPR.
// ---------------------------------------------------------------------------
__global__ __launch_bounds__(256) void partial_kernel(
    const void* __restrict__ w_hh,
    const void* __restrict__ w_sh, const void* __restrict__ b_sh,
    const void* __restrict__ hidden0, const void* __restrict__ stack,
    float* __restrict__ acc) {
    const bool f32 = detect_f32(w_hh);
    const int t = threadIdx.x, wave = t >> 6, lane = t & 63;
    const int p     = blockIdx.x / BPP;
    const int rbase = ((blockIdx.x % BPP) * 4 + wave) * RPW;

    // ---- h_bar slice (8 elems) into registers -----------------------------
    const float s0 = ldf(stack, 0, f32);
    const float s1 = ldf(stack, 1, f32);
    const float s2 = ldf(stack, 2, f32);
    const int j0 = p * PW + lane * 8;
    float hs[8];
    #pragma unroll
    for (int e = 0; e < 8; ++e) {
        const int j = j0 + e;
        hs[e] = ldf(w_sh, (size_t)j * 3 + 0, f32) * s0
              + ldf(w_sh, (size_t)j * 3 + 1, f32) * s1
              + ldf(w_sh, (size_t)j * 3 + 2, f32) * s2
              + ldf(b_sh, j, f32) + ldf(hidden0, j, f32);
    }
    const float4 h0 = make_float4(hs[0], hs[1], hs[2], hs[3]);
    const float4 h1 = make_float4(hs[4], hs[5], hs[6], hs[7]);

    // ---- stream 12 rows in chunks of 4 ------------------------------------
    if (f32) {
        const float4* W = (const float4*)w_hh;
        #pragma unroll
        for (int c = 0; c < RPW / 4; ++c) {
            const int r = rbase + c * 4;
            const size_t base = ((size_t)r * H + p * PW) / 4 + lane * 2;
            const size_t strd = H / 4;
            const float4 a0 = W[base];            const float4 b0 = W[base + 1];
            const float4 a1 = W[base + strd];     const float4 b1 = W[base + strd + 1];
            const float4 a2 = W[base + 2*strd];   const float4 b2 = W[base + 2*strd + 1];
            const float4 a3 = W[base + 3*strd];   const float4 b3 = W[base + 3*strd + 1];
            float v0 = a0.x*h0.x + a0.y*h0.y + a0.z*h0.z + a0.w*h0.w
                     + b0.x*h1.x + b0.y*h1.y + b0.z*h1.z + b0.w*h1.w;
            float v1 = a1.x*h0.x + a1.y*h0.y + a1.z*h0.z + a1.w*h0.w
                     + b1.x*h1.x + b1.y*h1.y + b1.z*h1.z + b1.w*h1.w;
            float v2 = a2.x*h0.x + a2.y*h0.y + a2.z*h0.z + a2.w*h0.w
                     + b2.x*h1.x + b2.y*h1.y + b2.z*h1.z + b2.w*h1.w;
            float v3 = a3.x*h0.x + a3.y*h0.y + a3.z*h0.z + a3.w*h0.w
                     + b3.x*h1.x + b3.y*h1.y + b3.z*h1.z + b3.w*h1.w;
            v0 = wave_reduce(v0); v1 = wave_reduce(v1);
            v2 = wave_reduce(v2); v3 = wave_reduce(v3);
            if (lane == 0) {
                atomicAdd(&acc[r],     v0);
                atomicAdd(&acc[r + 1], v1);
                atomicAdd(&acc[r + 2], v2);
                atomicAdd(&acc[r + 3], v3);
            }
        }
    } else {
        const uint4* W = (const uint4*)w_hh;
        #pragma unroll
        for (int c = 0; c < RPW / 4; ++c) {
            const int r = rbase + c * 4;
            const size_t base = ((size_t)r * H + p * PW) / 8 + lane;
            const size_t strd = H / 8;
            const uint4 a0 = W[base];
            const uint4 a1 = W[base + strd];
            const uint4 a2 = W[base + 2 * strd];
            const uint4 a3 = W[base + 3 * strd];
            float v0 = dot8(a0, h0, h1);
            float v1 = dot8(a1, h0, h1);
            float v2 = dot8(a2, h0, h1);
            float v3 = dot8(a3, h0, h1);
            v0 = wave_reduce(v0); v1 = wave_reduce(v1);
            v2 = wave_reduce(v2); v3 = wave_reduce(v3);
            if (lane == 0) {
                atomicAdd(&acc[r],     v0);
                atomicAdd(&acc[r + 1], v1);
                atomicAdd(&acc[r + 2], v2);
                atomicAdd(&acc[r + 3], v3);
            }
        }
    }
}

// ---------------------------------------------------------------------------
// Gates: thread k reads the 3 accumulated row-dots, recomputes h_bar[k]
// (6 cheap L2-hot loads), finishes the GRU cell. 16 blocks x 256.
// ---------------------------------------------------------------------------
__global__ __launch_bounds__(256) void gates_kernel(
    const int*  __restrict__ inp,  const void* __restrict__ emb,
    const void* __restrict__ w_ih, const void* __restrict__ w_hh,
    const void* __restrict__ b_ih, const void* __restrict__ b_hh,
    const void* __restrict__ w_sh, const void* __restrict__ b_sh,
    const void* __restrict__ hidden0, const void* __restrict__ stack,
    const float* __restrict__ acc,
    float* __restrict__ h_f32, void* __restrict__ out) {
    const bool f32 = detect_f32(w_hh);
    const int k = blockIdx.x * 256 + threadIdx.x;

    const float sr = acc[k];
    const float sz = acc[k + H];
    const float sn = acc[k + 2 * H];

    const float s0 = ldf(stack, 0, f32);
    const float s1 = ldf(stack, 1, f32);
    const float s2 = ldf(stack, 2, f32);
    const float hbk = ldf(w_sh, (size_t)k * 3 + 0, f32) * s0
                    + ldf(w_sh, (size_t)k * 3 + 1, f32) * s1
                    + ldf(w_sh, (size_t)k * 3 + 2, f32) * s2
                    + ldf(b_sh, k, f32) + ldf(hidden0, k, f32);

    const int idx = inp[0];
    float x[V];
    #pragma unroll
    for (int c = 0; c < V; ++c) x[c] = ldf(emb, (size_t)idx * V + c, f32);

    float gi[3];
    #pragma unroll
    for (int g = 0; g < 3; ++g) {
        float a = ldf(b_ih, (size_t)(k + g * H), f32);
        #pragma unroll
        for (int c = 0; c < V; ++c)
            a += ldf(w_ih, (size_t)(k + g * H) * V + c, f32) * x[c];
        gi[g] = a;
    }
    const float ghr = sr + ldf(b_hh, (size_t)k,           f32);
    const float ghz = sz + ldf(b_hh, (size_t)(k + H),     f32);
    const float ghn = sn + ldf(b_hh, (size_t)(k + 2 * H), f32);

    const float r = 1.f / (1.f + expf(-(gi[0] + ghr)));
    const float z = 1.f / (1.f + expf(-(gi[1] + ghz)));
    const float n = tanhf(gi[2] + r * ghn);
    const float hk = (1.f - z) * n + z * hbk;

    h_f32[k] = hk;
    stf(out, (size_t)(OUT_N + k), f32, hk);   // hidden output
}

// ---------------------------------------------------------------------------
// Heads: one row-dot per WAVE (9 of 16 waves active), single barrier, then
// sigmoid/softmax + differentiable stack blend. ~144 KB cold reads.
// ---------------------------------------------------------------------------
__global__ __launch_bounds__(1024) void heads_kernel(
    const float* __restrict__ h,
    const void* __restrict__ w_y, const void* __restrict__ b_y,
    const void* __restrict__ w_a, const void* __restrict__ b_a,
    const void* __restrict__ w_n, const void* __restrict__ b_n,
    const void* __restrict__ stack, const void* __restrict__ w_hh,
    void* __restrict__ out) {
    const bool f32 = detect_f32(w_hh);
    const int t = threadIdx.x, wave = t >> 6, lane = t & 63;

    __shared__ float scal[9];
    if (wave < 9) {
        const void* base; size_t row;
        if (wave < 4)      { base = w_y; row = (size_t)wave * H; }
        else if (wave < 6) { base = w_a; row = (size_t)(wave - 4) * H; }
        else               { base = w_n; row = (size_t)(wave - 6) * H; }

        float acc = 0.f;
        if (f32) {
            const float4* W  = (const float4*)((const float*)base + row);
            const float4* Hv = (const float4*)h;
            #pragma unroll 4
            for (int it = 0; it < H / 256; ++it) {
                const int i = (it << 6) + lane;
                const float4 a = W[i], hb = Hv[i];
                acc += a.x * hb.x + a.y * hb.y + a.z * hb.z + a.w * hb.w;
            }
        } else {
            const uint4*  W  = (const uint4*)((const unsigned short*)base + row);
            const float4* Hv = (const float4*)h;
            #pragma unroll 2
            for (int it = 0; it < H / 512; ++it) {
                const int i = (it << 6) + lane;
                acc += dot8(W[i], Hv[2 * i], Hv[2 * i + 1]);
            }
        }
        acc = wave_reduce(acc);
        if (lane == 0) scal[wave] = acc;
    }
    __syncthreads();

    __shared__ float act0, act1, ne[MD];
    if (t == 0) {
        const float a0 = scal[4] + ldf(b_a, 0, f32);
        const float a1 = scal[5] + ldf(b_a, 1, f32);
        const float m  = fmaxf(a0, a1);
        const float e0 = expf(a0 - m), e1 = expf(a1 - m);
        const float inv = 1.f / (e0 + e1);
        act0 = e0 * inv; act1 = e1 * inv;
    }
    if (t < OUT_N)
        stf(out, (size_t)t, f32,
            1.f / (1.f + expf(-(scal[t] + ldf(b_y, t, f32)))));
    if (t < MD)
        ne[t] = 1.f / (1.f + expf(-(scal[6 + t] + ldf(b_n, t, f32))));
    __syncthreads();

    const float a0 = act0, a1 = act1;
    for (int idx = t; idx < MS * MD; idx += 1024) {
        const int i = idx / MD;
        const int d = idx - i * MD;
        const float push = (i == 0)      ? ne[d] : ldf(stack, (size_t)(idx - MD), f32);
        const float pop  = (i == MS - 1) ? 0.f   : ldf(stack, (size_t)(idx + MD), f32);
        stf(out, (size_t)(OUT_N + H + idx), f32, a0 * push + a1 * pop);
    }
}

extern "C" void kernel_launch(void* const* d_in, const int* in_sizes, int n_in,
                              void* d_out, int out_size, void* d_ws, size_t ws_size,
                              hipStream_t stream) {
    const int* inp      = (const int*)d_in[0];
    const void* hidden0 = d_in[1];
    const void* stack   = d_in[2];
    const void* emb     = d_in[3];
    const void* w_ih    = d_in[4];
    const void* w_hh    = d_in[5];
    const void* b_ih    = d_in[6];
    const void* b_hh    = d_in[7];
    const void* w_y     = d_in[8];
    const void* b_y     = d_in[9];
    const void* w_n     = d_in[10];
    const void* b_n     = d_in[11];
    const void* w_a     = d_in[12];
    const void* b_a     = d_in[13];
    const void* w_sh    = d_in[14];
    const void* b_sh    = d_in[15];

    float* acc = (float*)d_ws;        // 3H fp32 = 48 KB
    float* h   = acc + R3H;           // H fp32 = 16 KB   (total 64 KB ws)

    zero_kernel<<<R3H / 256, 256, 0, stream>>>(acc);
    partial_kernel<<<P * BPP, 256, 0, stream>>>(w_hh, w_sh, b_sh, hidden0,
                                                stack, acc);
    gates_kernel<<<H / 256, 256, 0, stream>>>(inp, emb, w_ih, w_hh, b_ih, b_hh,
                                              w_sh, b_sh, hidden0, stack,
                                              acc, h, d_out);
    heads_kernel<<<1, 1024, 0, stream>>>(h, w_y, b_y, w_a, b_a, w_n, b_n,
                                         stack, w_hh, d_out);
}

// Round 6
// 313.991 us; speedup vs baseline: 1.1959x; 1.0547x over previous
//
#include <hip/hip_runtime.h>
#include <hip/hip_bf16.h>

#define H  4096
#define V  4
#define OUT_N 4
#define MS 104
#define MD 3

__device__ __forceinline__ float b2f(unsigned short u) {
    return __uint_as_float(((unsigned int)u) << 16);
}
__device__ __forceinline__ float ldf(const void* p, size_t i, bool is_f32) {
    return is_f32 ? ((const float*)p)[i] : b2f(((const unsigned short*)p)[i]);
}
__device__ __forceinline__ void stf(void* p, size_t i, bool is_f32, float v) {
    if (is_f32) ((float*)p)[i] = v;
    else        ((__hip_bfloat16*)p)[i] = __float2bfloat16(v);
}

// Wave-uniform dtype detection: decode first 1024 ushorts of w_hh as bf16.
// Real bf16 weights are all |x| <~ 0.2; f32 storage yields random-exponent
// halves (42%/elem chance of |x|>1e6). 2 KB, L1/L2-hot after first wave.
__device__ __forceinline__ bool detect_f32(const void* w_hh) {
    const unsigned short* w = (const unsigned short*)w_hh;
    const int lane = threadIdx.x & 63;
    int bad = 0;
    #pragma unroll
    for (int i = 0; i < 16; ++i) {
        const float v = b2f(w[lane + (i << 6)]);
        if (!(fabsf(v) < 1.0e6f)) bad = 1;
    }
    return __ballot(bad) != 0ull;
}

// 8 bf16 (as uint4) dotted against 8 f32 (two float4).
__device__ __forceinline__ float dot8(uint4 a, float4 h0, float4 h1) {
    return __uint_as_float(a.x << 16)          * h0.x
         + __uint_as_float(a.x & 0xffff0000u)  * h0.y
         + __uint_as_float(a.y << 16)          * h0.z
         + __uint_as_float(a.y & 0xffff0000u)  * h0.w
         + __uint_as_float(a.z << 16)          * h1.x
         + __uint_as_float(a.z & 0xffff0000u)  * h1.y
         + __uint_as_float(a.w << 16)          * h1.z
         + __uint_as_float(a.w & 0xffff0000u)  * h1.w;
}

__device__ __forceinline__ float dot4(float4 a, float4 b) {
    return a.x * b.x + a.y * b.y + a.z * b.z + a.w * b.w;
}

__device__ __forceinline__ float wave_reduce(float a) {
    #pragma unroll
    for (int off = 32; off > 0; off >>= 1) a += __shfl_down(a, off);
    return a;
}

// ---------------------------------------------------------------------------
// h_bar[j] = w_sh[j,:] . stack[0,:] + b_sh[j] + hidden0[j]  (fp32 into ws).
// 80 KB total traffic, computed once. 16 blocks x 256.
// ---------------------------------------------------------------------------
__global__ __launch_bounds__(256) void hbar_kernel(
    const void* __restrict__ w_sh, const void* __restrict__ b_sh,
    const void* __restrict__ hidden0, const void* __restrict__ stack,
    const void* __restrict__ w_hh, float* __restrict__ h_bar) {
    const bool f32 = detect_f32(w_hh);
    const float s0 = ldf(stack, 0, f32);
    const float s1 = ldf(stack, 1, f32);
    const float s2 = ldf(stack, 2, f32);
    const int j = blockIdx.x * 256 + threadIdx.x;   // grid is exactly H/256
    h_bar[j] = ldf(w_sh, (size_t)j * 3 + 0, f32) * s0
             + ldf(w_sh, (size_t)j * 3 + 1, f32) * s1
             + ldf(w_sh, (size_t)j * 3 + 2, f32) * s2
             + ldf(b_sh, j, f32) + ldf(hidden0, j, f32);
}

// ---------------------------------------------------------------------------
// One WAVE per hidden index k. NEW inner structure vs the 314 µs baseline:
//   1. h_bar slice preloaded into 64 VGPRs per lane (L2-hot, one-time) so
//      the streaming vmcnt queue holds ONLY w_hh loads.
//   2. 12 independent w_hh loads (3 rows x 4 iters, explicit variables,
//      constant indices) issued before any FMA -> 192 B/lane in flight,
//      3-4x the old depth. ~130 VGPR -> 3 waves/SIMD, 12 waves/CU.
// 1024 blocks x 256 thr (4 waves).
// ---------------------------------------------------------------------------
__global__ __launch_bounds__(256) void gru_kernel(
    const int*  __restrict__ inp,  const void* __restrict__ emb,
    const void* __restrict__ w_ih, const void* __restrict__ w_hh,
    const void* __restrict__ b_ih, const void* __restrict__ b_hh,
    const float* __restrict__ h_bar, float* __restrict__ h_f32,
    void* __restrict__ out) {
    const bool f32 = detect_f32(w_hh);
    const int wave = threadIdx.x >> 6, lane = threadIdx.x & 63;
    const int k = (blockIdx.x << 2) + wave;

    float ar = 0.f, az = 0.f, an = 0.f;
    if (f32) {
        // h_bar: lane slice = elems {i*256 + lane*4 .. +3}, i = 0..15.
        const float4* HB = (const float4*)h_bar;
        float4 hb[16];
        #pragma unroll
        for (int i = 0; i < 16; ++i) hb[i] = HB[i * 64 + lane];

        const float4* W0 = (const float4*)w_hh + (size_t)k           * (H / 4);
        const float4* W1 = (const float4*)w_hh + (size_t)(k + H)     * (H / 4);
        const float4* W2 = (const float4*)w_hh + (size_t)(k + 2 * H) * (H / 4);
        #pragma unroll
        for (int c = 0; c < 4; ++c) {            // 4 chunks x 4 iters
            float4 a0, a1, a2, a3, b0, b1, b2, b3, d0, d1, d2, d3;
            const int i0 = (c * 4 + 0) * 64 + lane;
            const int i1 = (c * 4 + 1) * 64 + lane;
            const int i2 = (c * 4 + 2) * 64 + lane;
            const int i3 = (c * 4 + 3) * 64 + lane;
            a0 = W0[i0]; a1 = W0[i1]; a2 = W0[i2]; a3 = W0[i3];
            b0 = W1[i0]; b1 = W1[i1]; b2 = W1[i2]; b3 = W1[i3];
            d0 = W2[i0]; d1 = W2[i1]; d2 = W2[i2]; d3 = W2[i3];
            ar += dot4(a0, hb[c*4+0]) + dot4(a1, hb[c*4+1])
                + dot4(a2, hb[c*4+2]) + dot4(a3, hb[c*4+3]);
            az += dot4(b0, hb[c*4+0]) + dot4(b1, hb[c*4+1])
                + dot4(b2, hb[c*4+2]) + dot4(b3, hb[c*4+3]);
            an += dot4(d0, hb[c*4+0]) + dot4(d1, hb[c*4+1])
                + dot4(d2, hb[c*4+2]) + dot4(d3, hb[c*4+3]);
        }
    } else {
        // h_bar: lane slice = elems {i*512 + lane*8 .. +7}, i = 0..7.
        const float4* HB = (const float4*)h_bar;
        float4 hb0[8], hb1[8];
        #pragma unroll
        for (int i = 0; i < 8; ++i) {
            hb0[i] = HB[i * 128 + lane * 2];
            hb1[i] = HB[i * 128 + lane * 2 + 1];
        }

        const uint4* W0 = (const uint4*)w_hh + (size_t)k           * (H / 8);
        const uint4* W1 = (const uint4*)w_hh + (size_t)(k + H)     * (H / 8);
        const uint4* W2 = (const uint4*)w_hh + (size_t)(k + 2 * H) * (H / 8);
        #pragma unroll
        for (int c = 0; c < 2; ++c) {            // 2 chunks x 4 iters
            uint4 a0, a1, a2, a3, b0, b1, b2, b3, d0, d1, d2, d3;
            const int i0 = (c * 4 + 0) * 64 + lane;
            const int i1 = (c * 4 + 1) * 64 + lane;
            const int i2 = (c * 4 + 2) * 64 + lane;
            const int i3 = (c * 4 + 3) * 64 + lane;
            a0 = W0[i0]; a1 = W0[i1]; a2 = W0[i2]; a3 = W0[i3];
            b0 = W1[i0]; b1 = W1[i1]; b2 = W1[i2]; b3 = W1[i3];
            d0 = W2[i0]; d1 = W2[i1]; d2 = W2[i2]; d3 = W2[i3];
            ar += dot8(a0, hb0[c*4+0], hb1[c*4+0]) + dot8(a1, hb0[c*4+1], hb1[c*4+1])
                + dot8(a2, hb0[c*4+2], hb1[c*4+2]) + dot8(a3, hb0[c*4+3], hb1[c*4+3]);
            az += dot8(b0, hb0[c*4+0], hb1[c*4+0]) + dot8(b1, hb0[c*4+1], hb1[c*4+1])
                + dot8(b2, hb0[c*4+2], hb1[c*4+2]) + dot8(b3, hb0[c*4+3], hb1[c*4+3]);
            an += dot8(d0, hb0[c*4+0], hb1[c*4+0]) + dot8(d1, hb0[c*4+1], hb1[c*4+1])
                + dot8(d2, hb0[c*4+2], hb1[c*4+2]) + dot8(d3, hb0[c*4+3], hb1[c*4+3]);
        }
    }

    ar = wave_reduce(ar);
    az = wave_reduce(az);
    an = wave_reduce(an);

    if (lane == 0) {
        const int idx = inp[0];
        float x[V];
        #pragma unroll
        for (int c = 0; c < V; ++c) x[c] = ldf(emb, (size_t)idx * V + c, f32);

        float gi[3];
        #pragma unroll
        for (int g = 0; g < 3; ++g) {
            float a = ldf(b_ih, (size_t)(k + g * H), f32);
            #pragma unroll
            for (int c = 0; c < V; ++c)
                a += ldf(w_ih, (size_t)(k + g * H) * V + c, f32) * x[c];
            gi[g] = a;
        }
        const float ghr = ar + ldf(b_hh, (size_t)k,           f32);
        const float ghz = az + ldf(b_hh, (size_t)(k + H),     f32);
        const float ghn = an + ldf(b_hh, (size_t)(k + 2 * H), f32);

        const float r = 1.f / (1.f + expf(-(gi[0] + ghr)));
        const float z = 1.f / (1.f + expf(-(gi[1] + ghz)));
        const float n = tanhf(gi[2] + r * ghn);
        const float hk = (1.f - z) * n + z * h_bar[k];

        h_f32[k] = hk;
        stf(out, (size_t)(OUT_N + k), f32, hk);   // hidden output
    }
}

// ---------------------------------------------------------------------------
// Heads: one row-dot per WAVE (9 of 16 waves active), single barrier, then
// sigmoid/softmax + differentiable stack blend. ~72-144 KB cold reads.
// ---------------------------------------------------------------------------
__global__ __launch_bounds__(1024) void heads_kernel(
    const float* __restrict__ h,
    const void* __restrict__ w_y, const void* __restrict__ b_y,
    const void* __restrict__ w_a, const void* __restrict__ b_a,
    const void* __restrict__ w_n, const void* __restrict__ b_n,
    const void* __restrict__ stack, const void* __restrict__ w_hh,
    void* __restrict__ out) {
    const bool f32 = detect_f32(w_hh);
    const int t = threadIdx.x, wave = t >> 6, lane = t & 63;

    __shared__ float scal[9];
    if (wave < 9) {
        const void* base; size_t row;
        if (wave < 4)      { base = w_y; row = (size_t)wave * H; }
        else if (wave < 6) { base = w_a; row = (size_t)(wave - 4) * H; }
        else               { base = w_n; row = (size_t)(wave - 6) * H; }

        float acc = 0.f;
        if (f32) {
            const float4* W  = (const float4*)((const float*)base + row);
            const float4* Hv = (const float4*)h;
            #pragma unroll 4
            for (int it = 0; it < H / 256; ++it) {
                const int i = (it << 6) + lane;
                acc += dot4(W[i], Hv[i]);
            }
        } else {
            const uint4*  W  = (const uint4*)((const unsigned short*)base + row);
            const float4* Hv = (const float4*)h;
            #pragma unroll 2
            for (int it = 0; it < H / 512; ++it) {
                const int i = (it << 6) + lane;
                acc += dot8(W[i], Hv[2 * i], Hv[2 * i + 1]);
            }
        }
        acc = wave_reduce(acc);
        if (lane == 0) scal[wave] = acc;
    }
    __syncthreads();

    __shared__ float act0, act1, ne[MD];
    if (t == 0) {
        const float a0 = scal[4] + ldf(b_a, 0, f32);
        const float a1 = scal[5] + ldf(b_a, 1, f32);
        const float m  = fmaxf(a0, a1);
        const float e0 = expf(a0 - m), e1 = expf(a1 - m);
        const float inv = 1.f / (e0 + e1);
        act0 = e0 * inv; act1 = e1 * inv;
    }
    if (t < OUT_N)
        stf(out, (size_t)t, f32,
            1.f / (1.f + expf(-(scal[t] + ldf(b_y, t, f32)))));
    if (t < MD)
        ne[t] = 1.f / (1.f + expf(-(scal[6 + t] + ldf(b_n, t, f32))));
    __syncthreads();

    const float a0 = act0, a1 = act1;
    for (int idx = t; idx < MS * MD; idx += 1024) {
        const int i = idx / MD;
        const int d = idx - i * MD;
        const float push = (i == 0)      ? ne[d] : ldf(stack, (size_t)(idx - MD), f32);
        const float pop  = (i == MS - 1) ? 0.f   : ldf(stack, (size_t)(idx + MD), f32);
        stf(out, (size_t)(OUT_N + H + idx), f32, a0 * push + a1 * pop);
    }
}

extern "C" void kernel_launch(void* const* d_in, const int* in_sizes, int n_in,
                              void* d_out, int out_size, void* d_ws, size_t ws_size,
                              hipStream_t stream) {
    const int* inp      = (const int*)d_in[0];
    const void* hidden0 = d_in[1];
    const void* stack   = d_in[2];
    const void* emb     = d_in[3];
    const void* w_ih    = d_in[4];
    const void* w_hh    = d_in[5];
    const void* b_ih    = d_in[6];
    const void* b_hh    = d_in[7];
    const void* w_y     = d_in[8];
    const void* b_y     = d_in[9];
    const void* w_n     = d_in[10];
    const void* b_n     = d_in[11];
    const void* w_a     = d_in[12];
    const void* b_a     = d_in[13];
    const void* w_sh    = d_in[14];
    const void* b_sh    = d_in[15];

    float* h_bar = (float*)d_ws;          // H fp32
    float* h     = h_bar + H;             // H fp32   (32 KB total workspace)

    hbar_kernel<<<H / 256, 256, 0, stream>>>(w_sh, b_sh, hidden0, stack,
                                             w_hh, h_bar);
    gru_kernel<<<H / 4, 256, 0, stream>>>(inp, emb, w_ih, w_hh, b_ih, b_hh,
                                          h_bar, h, d_out);
    heads_kernel<<<1, 1024, 0, stream>>>(h, w_y, b_y, w_a, b_a, w_n, b_n,
                                         stack, w_hh, d_out);
}